// Round 11
// baseline (147.438 us; speedup 1.0000x reference)
//
#include <hip/hip_runtime.h>
#include <math.h>

// ---------------- problem constants ----------------
#define NROWS  23328           // 8 * 54 * 54
#define SPAT   2916            // 54*54 rows per batch
#define HIN    56
#define IMG    3136            // 56*56
#define CIMG   200704          // 64*3136
#define NOUT   2985984         // 23328*128
#define RBPB   92              // 32-row blocks per batch (last has 4 valid)
#define NCH    54              // chunks (full K: 648 planes / 12)

// ---------------- ws layout (bytes) ----------------
#define W2_OFF    0u                         // [648][128][8] bf16 = 1327104
#define ACT8_OFF  1335296u                   // [NPIX][8] bf16 = 25690112
#define SILU_OFF  27025408u                  // [NHW][64] bf16 = 3211264
#define WS_NEED   30236672u                  // 30.2 MB (ws=268 MB proven by fill)

// prep flat-index ranges (512-thread blocks; first 392 blocks = silu tiles)
#define PREP_SIL_BLOCKS 392                  // 392*512 = 200704 = NHW*8 slots
#define R_SIL_END  200704
#define R_W2_END   864256                    // +663552 W2 entries
#define R_ACT_END  1265664                   // +401408 act8 float4-groups
#define PREP_BLOCKS (R_ACT_END / 512)        // 2472

typedef __bf16 bf16x8 __attribute__((ext_vector_type(8)));
typedef float  floatx4 __attribute__((ext_vector_type(4)));

#define GL2LDS(SRC, DST) __builtin_amdgcn_global_load_lds( \
    (const __attribute__((address_space(1))) unsigned int*)(SRC), \
    (__attribute__((address_space(3))) unsigned int*)(DST), 16, 0, 0)

__device__ __forceinline__ float silu_f(float p) {
    return p / (1.f + __expf(-p));
}

__device__ __forceinline__ bf16x8 bases8(float p) {
    float u  = p * 2.5f + 5.5f;              // uniform grid [-2.2,2.2], h=0.4
    float fk = floorf(u);
    int   kk = (int)fk;
    float t  = u - fk;
    float t2 = t * t, t3 = t2 * t;
    float omt = 1.f - t;
    float w0 = omt * omt * omt * (1.f / 6.f);
    float w1 = (3.f * t3 - 6.f * t2 + 4.f) * (1.f / 6.f);
    float w2 = (-3.f * t3 + 3.f * t2 + 3.f * t + 1.f) * (1.f / 6.f);
    float w3 = t3 * (1.f / 6.f);
    bool inr = (u >= 0.f) && (u < 11.f);
    bf16x8 v;
#pragma unroll
    for (int g = 0; g < 8; ++g) {
        int d = kk - g;
        float val = (d == 3) ? w0 : (d == 2) ? w1
                  : (d == 1) ? w2 : (d == 0) ? w3 : 0.f;
        v[g] = (__bf16)(inr ? val : 0.f);
    }
    return v;
}

// ---------------------------------------------------------------------------
// Prep (round-10 version, verified): 512-thread blocks.
//  * Blocks [0,392): silu transpose via LDS tile (64 hw x 64 ch).
//  * Blocks [392,..): flat idx — W2 planes, act8 planes (round-0 layouts).
// ---------------------------------------------------------------------------
__global__ __launch_bounds__(512) void prep_kernel(
    const float* __restrict__ x, const float* __restrict__ bw,
    const float* __restrict__ sw, const float* __restrict__ sc,
    char* __restrict__ ws)
{
    __bf16* W2    = (__bf16*)(ws + W2_OFF);
    __bf16* act8  = (__bf16*)(ws + ACT8_OFF);
    __bf16* silu_t= (__bf16*)(ws + SILU_OFF);

    if (blockIdx.x < PREP_SIL_BLOCKS) {
        __shared__ __bf16 tile[64 * 72];     // 64 hw x 64 ch, pad 72
        const int t   = threadIdx.x;
        const int T   = blockIdx.x;          // 64-row tile of NHW
        const int bt  = (T * 64) / IMG;      // IMG % 64 == 0 -> single batch
        const int hw0 = T * 64 - bt * IMG;

        // load + silu: lanes 0-15 = hw4 (16 x float4 = 256B contiguous)
        const int hw4 = t & 15;
        const int c0  = t >> 4;              // 0..31
#pragma unroll
        for (int cp = 0; cp < 2; ++cp) {
            int c = c0 + cp * 32;
            float4 v = *(const float4*)(x + (size_t)bt * CIMG + (size_t)c * IMG
                                          + hw0 + hw4 * 4);
            tile[(hw4 * 4 + 0) * 72 + c] = (__bf16)silu_f(v.x);
            tile[(hw4 * 4 + 1) * 72 + c] = (__bf16)silu_f(v.y);
            tile[(hw4 * 4 + 2) * 72 + c] = (__bf16)silu_f(v.z);
            tile[(hw4 * 4 + 3) * 72 + c] = (__bf16)silu_f(v.w);
        }
        __syncthreads();

        // write out: lanes 0-7 = cq -> one full 128B row per 8 lanes
        const int hw = t >> 3;
        const int cq = t & 7;
        bf16x8 o = *(const bf16x8*)(tile + hw * 72 + cq * 8);
        *(bf16x8*)(silu_t + ((size_t)bt * IMG + hw0 + hw) * 64 + cq * 8) = o;
        return;
    }

    int idx = blockIdx.x * 512 + threadIdx.x;   // continues at R_SIL_END
    if (idx < R_W2_END) {
        int iw = idx - R_SIL_END;
        int j  = iw & 7;
        int o  = (iw >> 3) & 127;
        int g  = iw >> 10;                   // 0..647
        float val;
        if (g < 576) {
            val = sw[(o * 576 + g) * 8 + j] * sc[o * 576 + g];
        } else {
            int eb = g - 576;
            int rs = eb >> 3;
            int c  = (eb & 7) * 8 + j;
            val = bw[o * 576 + c * 9 + rs];
        }
        W2[iw] = (__bf16)val;
    } else if (idx < R_ACT_END) {
        int i4 = idx - R_W2_END;
        float4 p = ((const float4*)x)[i4];
        __bf16* dst = act8 + (size_t)i4 * 32;
        *(bf16x8*)(dst)      = bases8(p.x);
        *(bf16x8*)(dst + 8)  = bases8(p.y);
        *(bf16x8*)(dst + 16) = bases8(p.z);
        *(bf16x8*)(dst + 24) = bases8(p.w);
    }
}

// ---------------------------------------------------------------------------
// GEMM: 736 blocks = 8 batches x 92 row-blocks, 256 threads (4 waves).
// batch = blockIdx & 7 -> batch-per-XCD L2 residency.
// Block = 32 rows x 128 couts x FULL K; wave = 32 rows x 32 couts (acc 2x2).
//
// Round-11 change: full-K blocks with direct output store — deletes the
// split-K machinery entirely (no partials, no reduce kernel, no extra
// launch gap; r8 proved atomics cost +37us, r9 proved fences thrash L2).
// Per-wave chunk structure (12 planes / 3 ks / gl2lds stage / one barrier)
// is r5's, with rows halved 64->32: A-planes are 512 B, so staging packs
// plane-PAIRS per 1 KB LDS slot (lane>>5 selects the plane; global src is
// per-lane — legal; LDS dest stays wave-uniform linear). Barrier count
// doubles (r7: barrier count is a don't-care) and W traffic returns to
// ~976 MB (r0 vs r4: traffic is a don't-care in this regime).
// ---------------------------------------------------------------------------
__global__ __launch_bounds__(256, 4) void kan_gemm(
    char* __restrict__ ws, float* __restrict__ outp)
{
    const __bf16* W2     = (const __bf16*)(ws + W2_OFF);
    const __bf16* act8   = (const __bf16*)(ws + ACT8_OFF);
    const __bf16* silu_t = (const __bf16*)(ws + SILU_OFF);

    __shared__ __align__(16) char As[2][6 * 1024];   // 2 x 6,144 B

    const int tid   = threadIdx.x;
    const int lane  = tid & 63;
    const int wave  = tid >> 6;          // 0..3 = coutg
    const int quad  = lane >> 4;
    const int l16   = lane & 15;
    const int l32   = lane & 31;         // local row for staging/compute
    const int hi    = lane >> 5;         // plane-within-pair for staging

    const int batch = blockIdx.x & 7;    // XCD affinity (round-robin %8)
    const int rb    = blockIdx.x >> 3;   // 0..91
    const int row0  = rb * 32;           // within batch

    // staging identity: lane -> (row = l32, plane-pair half = hi)
    const int rl0 = row0 + l32;
    const int rcl = rl0 < SPAT ? rl0 : SPAT - 1;
    const int ohh = rcl / 54, oww = rcl - (rcl / 54) * 54;
    const size_t pb = (size_t)batch * CIMG + ohh * HIN + oww;  // pixel index
    const size_t sb = ((size_t)batch * IMG + ohh * HIN + oww) * 64;

    floatx4 acc[2][2] = {};

    // chunk = 12 planes x 32 rows x 16 B = 6 pair-slots of 1 KB.
    // Wave w stages pair-slots {w} and {4+w : w<2} (wave-uniform LDS dest);
    // within a slot, lanes 0-31 stage plane 2*pr (rows 0-31), lanes 32-63
    // stage plane 2*pr+1 — per-lane global src, linear LDS dest.
    auto stage = [&](int chunkAbs, int buf) {
        int gbase = chunkAbs * 12;
#pragma unroll
        for (int t = 0; t < 2; ++t) {
            int pr = t * 4 + wave;           // pair-slot 0..5 (wave-uniform)
            if (pr >= 6) break;
            int p  = pr * 2 + hi;            // plane 0..11 (per-lane)
            int g  = gbase + p;              // global k/8 index 0..647
            const char* src;
            if (g < 576) {                   // spline planes
                int c  = g / 9;
                int rs = g - 9 * c;
                int rw = rs / 3;
                int off = c * IMG + rw * HIN + (rs - rw * 3);
                src = (const char*)(act8 + (pb + off) * 8);
            } else {                         // base/silu planes
                int eb = g - 576;
                int rs = eb >> 3;
                int rw = rs / 3;
                int off = (rw * HIN + (rs - rw * 3)) * 64 + (eb & 7) * 8;
                src = (const char*)(silu_t + sb + off);
            }
            GL2LDS(src, &As[buf][pr * 1024]);
        }
    };

    auto mfma_chunk = [&](int chunkAbs, int buf) {
        const char* Ab = (const char*)As[buf];
#pragma unroll
        for (int ks = 0; ks < 3; ++ks) {
            int p  = ks * 4 + quad;          // plane 0..11
            int gq = chunkAbs * 12 + p;
            bf16x8 wfr[2], afr[2];
#pragma unroll
            for (int nt = 0; nt < 2; ++nt)
                wfr[nt] = *(const bf16x8*)(W2 +
                    ((size_t)gq * 128 + wave * 32 + nt * 16 + l16) * 8);
#pragma unroll
            for (int mt = 0; mt < 2; ++mt)
                afr[mt] = *(const bf16x8*)(Ab +
                    (p >> 1) * 1024 + (p & 1) * 512 + (mt * 16 + l16) * 16);
#pragma unroll
            for (int mt = 0; mt < 2; ++mt)
#pragma unroll
                for (int nt = 0; nt < 2; ++nt)
                    acc[mt][nt] = __builtin_amdgcn_mfma_f32_16x16x32_bf16(
                        wfr[nt], afr[mt], acc[mt][nt], 0, 0, 0);
        }
    };

    stage(0, 0);
    __syncthreads();

    for (int i = 0; i < NCH; ++i) {
        const int buf = i & 1;
        if (i + 1 < NCH) stage(i + 1, buf ^ 1);   // async prefetch
        mfma_chunk(i, buf);
        __syncthreads();
    }

    // epilogue: DIRECT store (block owns full K of its tile).
    // D col(l16) = local row, D row(quad*4+r) = cout -> coalesced 64B runs.
#pragma unroll
    for (int mt = 0; mt < 2; ++mt) {
        int rl = row0 + mt * 16 + l16;       // row within batch
        if (rl < SPAT) {
#pragma unroll
            for (int nt = 0; nt < 2; ++nt) {
#pragma unroll
                for (int r = 0; r < 4; ++r) {
                    int o = wave * 32 + nt * 16 + quad * 4 + r;
                    outp[(size_t)(batch * 128 + o) * SPAT + rl] = acc[mt][nt][r];
                }
            }
        }
    }
}

extern "C" void kernel_launch(void* const* d_in, const int* in_sizes, int n_in,
                              void* d_out, int out_size, void* d_ws, size_t ws_size,
                              hipStream_t stream) {
    const float* x  = (const float*)d_in[0];
    const float* bw = (const float*)d_in[1];
    const float* sw = (const float*)d_in[2];
    const float* sc = (const float*)d_in[3];
    float* out = (float*)d_out;
    char*  ws  = (char*)d_ws;

    prep_kernel<<<PREP_BLOCKS, 512, 0, stream>>>(x, bw, sw, sc, ws);
    kan_gemm<<<8 * RBPB, 256, 0, stream>>>(ws, out);
}

// Round 12
// 134.483 us; speedup vs baseline: 1.0963x; 1.0963x over previous
//
#include <hip/hip_runtime.h>
#include <math.h>

// ---------------- problem constants ----------------
#define NROWS  23328           // 8 * 54 * 54
#define SPAT   2916            // 54*54 rows per batch
#define HIN    56
#define IMG    3136            // 56*56
#define CIMG   200704          // 64*3136
#define NOUT   2985984         // 23328*128
#define RBPB   46              // 64-row blocks per batch (last has 36 valid)
#define NKP    2               // K-pieces (halves)
#define NCH    27              // chunks per K-piece (648 planes / 12 / 2)

// ---------------- ws layout (bytes) ----------------
#define W2_OFF    0u                         // [648][128][8] bf16 = 1327104
#define ACT8_OFF  1335296u                   // [NPIX][8] bf16 = 25690112
#define SILU_OFF  27025408u                  // [NHW][64] bf16 = 3211264
#define PART_OFF  30236672u                  // [2][NOUT] f32 = 23887872
#define WS_NEED   (PART_OFF + 2u * NOUT * 4u)   // 54.1 MB (proven round 0)

// prep idx ranges
#define R_SIL_END  200704
#define R_W2_END   864256                    // +663552
#define R_ACT_END  1265664                   // +401408

typedef __bf16 bf16x8 __attribute__((ext_vector_type(8)));
typedef float  floatx4 __attribute__((ext_vector_type(4)));

#define GL2LDS(SRC, DST) __builtin_amdgcn_global_load_lds( \
    (const __attribute__((address_space(1))) unsigned int*)(SRC), \
    (__attribute__((address_space(3))) unsigned int*)(DST), 16, 0, 0)

__device__ __forceinline__ float silu_f(float p) {
    return p / (1.f + __expf(-p));
}

__device__ __forceinline__ bf16x8 bases8(float p) {
    float u  = p * 2.5f + 5.5f;              // uniform grid [-2.2,2.2], h=0.4
    float fk = floorf(u);
    int   kk = (int)fk;
    float t  = u - fk;
    float t2 = t * t, t3 = t2 * t;
    float omt = 1.f - t;
    float w0 = omt * omt * omt * (1.f / 6.f);
    float w1 = (3.f * t3 - 6.f * t2 + 4.f) * (1.f / 6.f);
    float w2 = (-3.f * t3 + 3.f * t2 + 3.f * t + 1.f) * (1.f / 6.f);
    float w3 = t3 * (1.f / 6.f);
    bool inr = (u >= 0.f) && (u < 11.f);
    bf16x8 v;
#pragma unroll
    for (int g = 0; g < 8; ++g) {
        int d = kk - g;
        float val = (d == 3) ? w0 : (d == 2) ? w1
                  : (d == 1) ? w2 : (d == 0) ? w3 : 0.f;
        v[g] = (__bf16)(inr ? val : 0.f);
    }
    return v;
}

// ---------------------------------------------------------------------------
// Prep: silu transpose, W2 planes ([g][cout][8], g = k/8), act8 planes.
// Round-5 version verbatim (r10's prep rework measured neutral).
// ---------------------------------------------------------------------------
__global__ __launch_bounds__(256) void prep_kernel(
    const float* __restrict__ x, const float* __restrict__ bw,
    const float* __restrict__ sw, const float* __restrict__ sc,
    char* __restrict__ ws)
{
    __bf16* W2    = (__bf16*)(ws + W2_OFF);
    __bf16* act8  = (__bf16*)(ws + ACT8_OFF);
    __bf16* silu_t= (__bf16*)(ws + SILU_OFF);

    int idx = blockIdx.x * 256 + threadIdx.x;
    if (idx < R_SIL_END) {
        int c8 = idx & 7;
        int r  = idx >> 3;                   // b*IMG + hw
        int b  = r / IMG;
        int hw = r - b * IMG;
        const float* xb = x + b * CIMG + (c8 * 8) * IMG + hw;
        bf16x8 v;
#pragma unroll
        for (int j = 0; j < 8; ++j) v[j] = (__bf16)silu_f(xb[j * IMG]);
        *(bf16x8*)(silu_t + (size_t)r * 64 + c8 * 8) = v;
    } else if (idx < R_W2_END) {
        int iw = idx - R_SIL_END;
        int j  = iw & 7;
        int o  = (iw >> 3) & 127;
        int g  = iw >> 10;                   // 0..647
        float val;
        if (g < 576) {
            val = sw[(o * 576 + g) * 8 + j] * sc[o * 576 + g];
        } else {
            int eb = g - 576;
            int rs = eb >> 3;
            int c  = (eb & 7) * 8 + j;
            val = bw[o * 576 + c * 9 + rs];
        }
        W2[iw] = (__bf16)val;
    } else if (idx < R_ACT_END) {
        int i4 = idx - R_W2_END;
        float4 p = ((const float4*)x)[i4];
        __bf16* dst = act8 + (size_t)i4 * 32;
        *(bf16x8*)(dst)      = bases8(p.x);
        *(bf16x8*)(dst + 8)  = bases8(p.y);
        *(bf16x8*)(dst + 16) = bases8(p.z);
        *(bf16x8*)(dst + 24) = bases8(p.w);
    }
}

// ---------------------------------------------------------------------------
// GEMM: 736 blocks = 8 batches x 46 row-blocks x 2 K-halves, 256 threads
// (4 waves). batch = blockIdx & 7 -> batch-per-XCD L2 residency.
// Block = 64 rows x 128 couts x half-K; wave = 64 rows x 32 couts (acc 4x2).
//
// Round-12: round-5's proven per-wave schedule (best of 12 structural
// variants: 64-row waves, 12-plane chunks = 466-cyc MFMA cover per barrier,
// gl2lds fire-and-forget double-buffer), with NKP 3 -> 2: halves the
// partial-slice write traffic (35.8 -> 23.9 MB) and the reduce's read
// traffic (36 -> 24 MB). Barrier-count axis (18 vs 27 chunks/block) proven
// a don't-care (r7); phase-cover and atomics/fences axes mapped r8-r11.
// ---------------------------------------------------------------------------
template <int MODE>
__global__ __launch_bounds__(256, 4) void kan_gemm(
    char* __restrict__ ws, float* __restrict__ outp)
{
    const __bf16* W2     = (const __bf16*)(ws + W2_OFF);
    const __bf16* act8   = (const __bf16*)(ws + ACT8_OFF);
    const __bf16* silu_t = (const __bf16*)(ws + SILU_OFF);
    float*        part   = (float*)(ws + PART_OFF);

    __shared__ __align__(16) char As[2][12 * 64 * 16];   // 2 x 12,288 B

    const int tid   = threadIdx.x;
    const int lane  = tid & 63;
    const int wave  = tid >> 6;          // 0..3 = coutg
    const int quad  = lane >> 4;
    const int l16   = lane & 15;

    const int batch = blockIdx.x & 7;    // XCD affinity (round-robin %8)
    const int t2    = blockIdx.x >> 3;   // 0..91
    const int kp    = t2 & 1;            // K-half
    const int rb    = t2 >> 1;           // 0..45
    const int row0  = rb * 64;           // within batch

    // staging identity: lane = local row, clamped to batch range
    const int rl0 = row0 + lane;
    const int rcl = rl0 < SPAT ? rl0 : SPAT - 1;
    const int ohh = rcl / 54, oww = rcl - (rcl / 54) * 54;
    const size_t pb = (size_t)batch * CIMG + ohh * HIN + oww;  // pixel index
    const size_t sb = ((size_t)batch * IMG + ohh * HIN + oww) * 64;

    floatx4 acc[4][2] = {};

    // chunk = 12 planes x 64 rows x 16 B = 12 slots of 1 KB.
    // Wave w stages planes {t*4 + w : t=0..2} (wave-uniform LDS dest).
    auto stage = [&](int chunkAbs, int buf) {
        int gbase = chunkAbs * 12;
#pragma unroll
        for (int t = 0; t < 3; ++t) {
            int p = t * 4 + wave;            // plane 0..11
            int g = gbase + p;               // global k/8 index 0..647
            const char* src;
            if (g < 576) {                   // spline planes
                int c  = g / 9;
                int rs = g - 9 * c;
                int rw = rs / 3;
                int off = c * IMG + rw * HIN + (rs - rw * 3);
                src = (const char*)(act8 + (pb + off) * 8);
            } else {                         // base/silu planes
                int eb = g - 576;
                int rs = eb >> 3;
                int rw = rs / 3;
                int off = (rw * HIN + (rs - rw * 3)) * 64 + (eb & 7) * 8;
                src = (const char*)(silu_t + sb + off);
            }
            GL2LDS(src, &As[buf][p * 1024]);
        }
    };

    auto mfma_chunk = [&](int chunkAbs, int buf) {
        const char* Ab = (const char*)As[buf];
#pragma unroll
        for (int ks = 0; ks < 3; ++ks) {
            int gq = (chunkAbs * 3 + ks) * 4 + quad;
            bf16x8 wfr[2], afr[4];
#pragma unroll
            for (int nt = 0; nt < 2; ++nt)
                wfr[nt] = *(const bf16x8*)(W2 +
                    ((size_t)gq * 128 + wave * 32 + nt * 16 + l16) * 8);
#pragma unroll
            for (int mt = 0; mt < 4; ++mt)
                afr[mt] = *(const bf16x8*)(Ab +
                    ((ks * 4 + quad) * 64 + mt * 16 + l16) * 16);
#pragma unroll
            for (int mt = 0; mt < 4; ++mt)
#pragma unroll
                for (int nt = 0; nt < 2; ++nt)
                    acc[mt][nt] = __builtin_amdgcn_mfma_f32_16x16x32_bf16(
                        wfr[nt], afr[mt], acc[mt][nt], 0, 0, 0);
        }
    };

    const int cstart = kp * NCH;

    stage(cstart, 0);
    __syncthreads();

    for (int i = 0; i < NCH; ++i) {
        const int buf = i & 1;
        if (i + 1 < NCH) stage(cstart + i + 1, buf ^ 1);   // async prefetch
        mfma_chunk(cstart + i, buf);
        __syncthreads();
    }

    // epilogue: D col(l16) = local row, D row(quad*4+r) = cout -> coalesced
#pragma unroll
    for (int mt = 0; mt < 4; ++mt) {
        int rl = row0 + mt * 16 + l16;       // row within batch
        if (rl < SPAT) {
#pragma unroll
            for (int nt = 0; nt < 2; ++nt) {
#pragma unroll
                for (int r = 0; r < 4; ++r) {
                    int o = wave * 32 + nt * 16 + quad * 4 + r;
                    size_t idx = (size_t)(batch * 128 + o) * SPAT + rl;
                    float v = acc[mt][nt][r];
                    if (MODE == 0) part[(size_t)kp * NOUT + idx] = v;
                    else           atomicAdd(&outp[idx], v);
                }
            }
        }
    }
}

__global__ __launch_bounds__(256) void reduce_kernel(
    const char* __restrict__ ws, float* __restrict__ outp)
{
    const floatx4* p0 = (const floatx4*)(ws + PART_OFF);
    const floatx4* p1 = p0 + NOUT / 4;
    int i = blockIdx.x * 256 + threadIdx.x;   // grid covers NOUT/4 exactly
    floatx4 a = p0[i], b = p1[i];
    ((floatx4*)outp)[i] = (floatx4){a[0] + b[0], a[1] + b[1],
                                    a[2] + b[2], a[3] + b[3]};
}

__global__ __launch_bounds__(256) void zero_kernel(float* __restrict__ outp)
{
    int i = blockIdx.x * 256 + threadIdx.x;
    ((floatx4*)outp)[i] = (floatx4){0.f, 0.f, 0.f, 0.f};
}

extern "C" void kernel_launch(void* const* d_in, const int* in_sizes, int n_in,
                              void* d_out, int out_size, void* d_ws, size_t ws_size,
                              hipStream_t stream) {
    const float* x  = (const float*)d_in[0];
    const float* bw = (const float*)d_in[1];
    const float* sw = (const float*)d_in[2];
    const float* sc = (const float*)d_in[3];
    float* out = (float*)d_out;
    char*  ws  = (char*)d_ws;

    prep_kernel<<<R_ACT_END / 256, 256, 0, stream>>>(x, bw, sw, sc, ws);

    if (ws_size >= WS_NEED) {
        kan_gemm<0><<<8 * RBPB * NKP, 256, 0, stream>>>(ws, out);
        reduce_kernel<<<NOUT / 4 / 256, 256, 0, stream>>>(ws, out);
    } else {
        zero_kernel<<<NOUT / 4 / 256, 256, 0, stream>>>(out);
        kan_gemm<1><<<8 * RBPB * NKP, 256, 0, stream>>>(ws, out);
    }
}